// Round 8
// baseline (501.549 us; speedup 1.0000x reference)
//
#include <hip/hip_runtime.h>
#include <math.h>

#define DIM 128
#define SCAN_CHUNK 4096  // 256 threads * 16 elems

typedef __attribute__((ext_vector_type(8))) short short8;
typedef __attribute__((ext_vector_type(4))) float f32x4;

__device__ __forceinline__ float gelu_exact(float v) {
    return 0.5f * v * (1.0f + erff(v * 0.70710678118654752f));
}

// round-to-nearest-even fp32 -> bf16 bits (finite inputs)
__device__ __forceinline__ unsigned short f2bf(float f) {
    unsigned int u = __float_as_uint(f);
    return (unsigned short)((u + 0x7FFFu + ((u >> 16) & 1u)) >> 16);
}
__device__ __forceinline__ float bf_lo(unsigned int v) { return __uint_as_float(v << 16); }
__device__ __forceinline__ float bf_hi(unsigned int v) { return __uint_as_float(v & 0xFFFF0000u); }

// ---------------- graph build ----------------
// packed[d]: high 32 = edge count, low 32 = sum(w) in 2^26 fixed point.
// One 64-bit atomic per edge; returned old high word = rank within segment.
// NOTE: standalone kernel, 1 edge/thread, 4 VGPR — co-residency with GEMM
// waves (R7 phase0) and 2-edge chains both hurt; keep this minimal.

__global__ void deg_cnt_kernel(const int* __restrict__ dst,
                               const float* __restrict__ w,
                               unsigned long long* __restrict__ packed,
                               int* __restrict__ rank, int E) {
    int e = blockIdx.x * blockDim.x + threadIdx.x;
    if (e >= E) return;
    int d = dst[e];
    unsigned long long inc =
        (1ull << 32) | (unsigned long long)(unsigned int)(w[e] * 67108864.0f);
    unsigned long long old = atomicAdd(&packed[d], inc);
    rank[e] = (int)(old >> 32);
}

// ---------------- weight transpose + bf16 (3 matrices, one launch) ----------------

__global__ __launch_bounds__(256) void wt3_kernel(const float* __restrict__ W1,
                                                  const float* __restrict__ Wres,
                                                  const float* __restrict__ W2,
                                                  unsigned short* __restrict__ Wt1,
                                                  unsigned short* __restrict__ Wtr,
                                                  unsigned short* __restrict__ Wt2) {
    int b = blockIdx.x;
    const float* W = (b < 64) ? W1 : (b < 128) ? Wres : W2;
    unsigned short* Wt = (b < 64) ? Wt1 : (b < 128) ? Wtr : Wt2;
    int idx = (b & 63) * 256 + threadIdx.x;  // idx = r*128 + c
    int r = idx >> 7, c = idx & 127;
    Wt[c * 128 + r] = f2bf(W[idx]);
}

// ---------------- MFMA GEMM body: [BN,128] @ [128,128] via bf16 16x16x32 ----------
// MODE 0: outb = bf16(X @ W)        MODE 2: Bf = 0.3f*(X@W + bias)   (init)

template <int MODE>
__device__ __forceinline__ void gemm_body(const float* __restrict__ X,
                                          const unsigned short* __restrict__ Wt,
                                          const float* __restrict__ bias,
                                          unsigned short* __restrict__ outb,
                                          float* __restrict__ Bf, int bid, int BN) {
    int tid = threadIdx.x;
    int w = tid >> 6, l = tid & 63;
    int l15 = l & 15, kg = l >> 4;
    int row0 = bid * 64 + w * 16;

    int rowA = row0 + l15;
    if (rowA > BN - 1) rowA = BN - 1;
    const float* ap = X + (size_t)rowA * 128 + kg * 8;

    f32x4 acc[8];
#pragma unroll
    for (int nt = 0; nt < 8; nt++) acc[nt] = (f32x4){0.f, 0.f, 0.f, 0.f};

#pragma unroll
    for (int ks = 0; ks < 4; ks++) {
        float4 a0 = *(const float4*)(ap + ks * 32);
        float4 a1 = *(const float4*)(ap + ks * 32 + 4);
        short8 aF;
        aF[0] = (short)f2bf(a0.x); aF[1] = (short)f2bf(a0.y);
        aF[2] = (short)f2bf(a0.z); aF[3] = (short)f2bf(a0.w);
        aF[4] = (short)f2bf(a1.x); aF[5] = (short)f2bf(a1.y);
        aF[6] = (short)f2bf(a1.z); aF[7] = (short)f2bf(a1.w);
#pragma unroll
        for (int nt = 0; nt < 8; nt++) {
            int colB = nt * 16 + l15;
            uint4 bu = *(const uint4*)(Wt + (size_t)colB * 128 + ks * 32 + kg * 8);
            short8 bF = __builtin_bit_cast(short8, bu);
            acc[nt] = __builtin_amdgcn_mfma_f32_16x16x32_bf16(aF, bF, acc[nt], 0, 0, 0);
        }
    }

#pragma unroll
    for (int nt = 0; nt < 8; nt++) {
        int col = nt * 16 + l15;
#pragma unroll
        for (int r = 0; r < 4; r++) {
            int row = row0 + kg * 4 + r;
            if (row >= BN) continue;
            size_t idx = (size_t)row * 128 + col;
            if (MODE == 0) {
                outb[idx] = f2bf(acc[nt][r]);
            } else {
                Bf[idx] = 0.3f * (acc[nt][r] + bias[col]);
            }
        }
    }
}

template <int MODE>
__global__ __launch_bounds__(256) void mfma_gemm_kernel(const float* __restrict__ X,
                                                        const unsigned short* __restrict__ Wt,
                                                        const float* __restrict__ bias,
                                                        unsigned short* __restrict__ outb,
                                                        float* __restrict__ Bf, int BN) {
    gemm_body<MODE>(X, Wt, bias, outb, Bf, blockIdx.x, BN);
}

// homogeneous fusion: blocks [0,gB) do x@W1 -> Ab; [gB,2gB) do res-init -> Bf
__global__ __launch_bounds__(256) void gemm2x_kernel(const float* __restrict__ x,
                                                     const unsigned short* __restrict__ Wt1,
                                                     const unsigned short* __restrict__ Wtr,
                                                     const float* __restrict__ bres,
                                                     unsigned short* __restrict__ Ab,
                                                     float* __restrict__ Bf,
                                                     int BN, int gB) {
    int b = blockIdx.x;
    if (b < gB) gemm_body<0>(x, Wt1, nullptr, Ab, nullptr, b, BN);
    else        gemm_body<2>(x, Wtr, bres, nullptr, Bf, b - gB, BN);
}

// ---------------- scan stage A (fused with dinv/cnt unpack) ----------------

__global__ __launch_bounds__(256) void scanAD_kernel(const unsigned long long* __restrict__ packed,
                                                     float* __restrict__ dinvf,
                                                     int* __restrict__ cnt,
                                                     int* __restrict__ partials, int BN) {
    int tid = threadIdx.x;
    int base = blockIdx.x * SCAN_CHUNK;
    int sum = 0;
#pragma unroll
    for (int i = 0; i < 16; i++) {
        int ii = base + i * 256 + tid;
        if (ii < BN) {
            unsigned long long v = packed[ii];
            int c = (int)(v >> 32);
            cnt[ii] = c;
            dinvf[ii] = rsqrtf((float)(unsigned int)(v & 0xFFFFFFFFu) * (1.0f / 67108864.0f) + 1.0f);
            sum += c;
        }
    }
    __shared__ int lds[4];
#pragma unroll
    for (int off = 32; off; off >>= 1) sum += __shfl_down(sum, off, 64);
    if ((tid & 63) == 0) lds[tid >> 6] = sum;
    __syncthreads();
    if (tid == 0) partials[blockIdx.x] = lds[0] + lds[1] + lds[2] + lds[3];
}

__global__ __launch_bounds__(256) void scanB_kernel(int* __restrict__ partials, int nblk) {
    __shared__ int lds[256];
    int tid = threadIdx.x;
    int v = (tid < nblk) ? partials[tid] : 0;
    lds[tid] = v;
    __syncthreads();
#pragma unroll
    for (int off = 1; off < 256; off <<= 1) {
        int t = (tid >= off) ? lds[tid - off] : 0;
        __syncthreads();
        lds[tid] += t;
        __syncthreads();
    }
    if (tid < nblk) partials[tid] = lds[tid] - v;  // exclusive
}

__global__ __launch_bounds__(256) void scanC_kernel(const int* __restrict__ cnt,
                                                    const int* __restrict__ partials,
                                                    int* __restrict__ ptr, int BN) {
    __shared__ int lds[256];
    int tid = threadIdx.x;
    int base = blockIdx.x * SCAN_CHUNK;
    int idx0 = base + tid * 16;
    int v[16];
    int tsum = 0;
#pragma unroll
    for (int j = 0; j < 16; j++) {
        int ii = idx0 + j;
        v[j] = (ii < BN) ? cnt[ii] : 0;
        tsum += v[j];
    }
    lds[tid] = tsum;
    __syncthreads();
#pragma unroll
    for (int off = 1; off < 256; off <<= 1) {
        int t = (tid >= off) ? lds[tid - off] : 0;
        __syncthreads();
        lds[tid] += t;
        __syncthreads();
    }
    int excl = lds[tid] - tsum + partials[blockIdx.x];
#pragma unroll
    for (int j = 0; j < 16; j++) {
        int ii = idx0 + j;
        if (ii < BN) ptr[ii] = excl;
        excl += v[j];
    }
}

// atomic-free fill: pos = ptr[d] + rank[e]; one packed int2 {src, nrm} per edge
__global__ void fill_kernel(const int* __restrict__ ei, const float* __restrict__ w,
                            const int* __restrict__ rank, const int* __restrict__ ptr,
                            const float* __restrict__ dinvf,
                            int2* __restrict__ csr, int E) {
    int e = blockIdx.x * blockDim.x + threadIdx.x;
    if (e >= E) return;
    int s = ei[e];
    int d = ei[(size_t)E + e];
    int pos = ptr[d] + rank[e];
    float nrm = dinvf[s] * w[e] * dinvf[d];
    csr[pos] = make_int2(s, __float_as_int(nrm));
}

// ---------------- aggregation: half-wave (32 lanes) per node, bf16 gather, 4-deep ----
// ACCMODE 0: out = gelu(...)        ACCMODE 1: out += gelu(...)

template <int ACCMODE>
__global__ __launch_bounds__(256) void agg_kernel(const unsigned short* __restrict__ XWb,
                                                  const float* __restrict__ dinvf,
                                                  const int* __restrict__ ptr,
                                                  const int* __restrict__ cnt,
                                                  const int2* __restrict__ csr,
                                                  const float* __restrict__ bias,
                                                  float* __restrict__ out, int BN) {
    int h = threadIdx.x >> 5;        // half-wave id 0..7
    int lane = threadIdx.x & 31;     // lane within half-wave
    int n = blockIdx.x * 8 + h;
    if (n >= BN) return;
    int beg = ptr[n];
    int endv = beg + cnt[n];

    float4 a0 = make_float4(0.f, 0.f, 0.f, 0.f);
    float4 a1 = make_float4(0.f, 0.f, 0.f, 0.f);
    float4 a2 = make_float4(0.f, 0.f, 0.f, 0.f);
    float4 a3 = make_float4(0.f, 0.f, 0.f, 0.f);
    int i = beg;
    for (; i + 3 < endv; i += 4) {
        int2 e0 = csr[i], e1 = csr[i + 1], e2 = csr[i + 2], e3 = csr[i + 3];
        uint2 r0 = *(const uint2*)(XWb + (size_t)e0.x * 128 + lane * 4);
        uint2 r1 = *(const uint2*)(XWb + (size_t)e1.x * 128 + lane * 4);
        uint2 r2 = *(const uint2*)(XWb + (size_t)e2.x * 128 + lane * 4);
        uint2 r3 = *(const uint2*)(XWb + (size_t)e3.x * 128 + lane * 4);
        float n0 = __int_as_float(e0.y), n1 = __int_as_float(e1.y);
        float n2 = __int_as_float(e2.y), n3 = __int_as_float(e3.y);
        a0.x += n0 * bf_lo(r0.x); a0.y += n0 * bf_hi(r0.x);
        a0.z += n0 * bf_lo(r0.y); a0.w += n0 * bf_hi(r0.y);
        a1.x += n1 * bf_lo(r1.x); a1.y += n1 * bf_hi(r1.x);
        a1.z += n1 * bf_lo(r1.y); a1.w += n1 * bf_hi(r1.y);
        a2.x += n2 * bf_lo(r2.x); a2.y += n2 * bf_hi(r2.x);
        a2.z += n2 * bf_lo(r2.y); a2.w += n2 * bf_hi(r2.y);
        a3.x += n3 * bf_lo(r3.x); a3.y += n3 * bf_hi(r3.x);
        a3.z += n3 * bf_lo(r3.y); a3.w += n3 * bf_hi(r3.y);
    }
    for (; i < endv; i++) {
        int2 e0 = csr[i];
        uint2 r0 = *(const uint2*)(XWb + (size_t)e0.x * 128 + lane * 4);
        float n0 = __int_as_float(e0.y);
        a0.x += n0 * bf_lo(r0.x); a0.y += n0 * bf_hi(r0.x);
        a0.z += n0 * bf_lo(r0.y); a0.w += n0 * bf_hi(r0.y);
    }
    float dn = dinvf[n];
    float sl = dn * dn;
    uint2 rs = *(const uint2*)(XWb + (size_t)n * 128 + lane * 4);
    float4 bb = ((const float4*)bias)[lane];
    float4 o;
    o.x = gelu_exact(a0.x + a1.x + a2.x + a3.x + sl * bf_lo(rs.x) + bb.x);
    o.y = gelu_exact(a0.y + a1.y + a2.y + a3.y + sl * bf_hi(rs.x) + bb.y);
    o.z = gelu_exact(a0.z + a1.z + a2.z + a3.z + sl * bf_lo(rs.y) + bb.z);
    o.w = gelu_exact(a0.w + a1.w + a2.w + a3.w + sl * bf_hi(rs.y) + bb.w);
    float4* op = (float4*)(out + (size_t)n * 128) + lane;
    if (ACCMODE == 1) {
        float4 prev = *op;
        o.x += prev.x; o.y += prev.y; o.z += prev.z; o.w += prev.w;
    }
    *op = o;
}

// ---------------- launch ----------------

extern "C" void kernel_launch(void* const* d_in, const int* in_sizes, int n_in,
                              void* d_out, int out_size, void* d_ws, size_t ws_size,
                              hipStream_t stream) {
    const float* x = (const float*)d_in[0];
    const int* ei = (const int*)d_in[1];        // harness passes integers as int32
    const float* w = (const float*)d_in[5];
    const float* W1 = (const float*)d_in[7];
    const float* b1 = (const float*)d_in[8];
    const float* W2 = (const float*)d_in[9];
    const float* b2 = (const float*)d_in[10];
    const float* Wres = (const float*)d_in[11];
    const float* bres = (const float*)d_in[12];

    const int BN = in_sizes[0] / DIM;
    const int E = in_sizes[1] / 2;
    const int NBLK = (BN + SCAN_CHUNK - 1) / SCAN_CHUNK;

    // workspace layout (16B aligned); h-buffer lives in d_out.
    char* p = (char*)d_ws;
    unsigned short* Ab = (unsigned short*)p;         p += (size_t)BN * DIM * 2;  // bf16 XW
    unsigned long long* packed = (unsigned long long*)p;  p += (size_t)BN * 8;
    float* dinvf = (float*)p;          p += (size_t)BN * 4;
    int* cnt = (int*)p;                p += (size_t)BN * 4;
    int* ptr = (int*)p;                p += (size_t)BN * 4;
    int* partials = (int*)p;           p += 1024;
    unsigned short* Wt1 = (unsigned short*)p;   p += 128 * 128 * 2;
    unsigned short* Wtr = (unsigned short*)p;   p += 128 * 128 * 2;
    unsigned short* Wt2 = (unsigned short*)p;   p += 128 * 128 * 2;
    int* rank = (int*)p;               p += (size_t)E * 4;
    int2* csr = (int2*)p;              p += (size_t)E * 8;

    float* Bf = (float*)d_out;         // h buffer; fully written by res-init

    const int* dst32 = ei + E;

    hipMemsetAsync(packed, 0, (size_t)BN * 8, stream);

    int tE = (E + 255) / 256;
    int gB = (BN + 63) / 64;
    int aggBlocks = (BN + 7) / 8;

    deg_cnt_kernel<<<tE, 256, 0, stream>>>(dst32, w, packed, rank, E);
    wt3_kernel<<<192, 256, 0, stream>>>(W1, Wres, W2, Wt1, Wtr, Wt2);

    // Ab = bf16(x@W1)  and  Bf = 0.3*(x@Wres+bres)  (homogeneous fusion)
    gemm2x_kernel<<<2 * gB, 256, 0, stream>>>(x, Wt1, Wtr, bres, Ab, Bf, BN, gB);

    scanAD_kernel<<<NBLK, 256, 0, stream>>>(packed, dinvf, cnt, partials, BN);
    scanB_kernel<<<1, 256, 0, stream>>>(partials, NBLK);
    scanC_kernel<<<NBLK, 256, 0, stream>>>(cnt, partials, ptr, BN);
    fill_kernel<<<tE, 256, 0, stream>>>(ei, w, rank, ptr, dinvf, csr, E);

    // layer 1 finish: Bf += gelu(agg(Ab) + b1)
    agg_kernel<1><<<aggBlocks, 256, 0, stream>>>(Ab, dinvf, ptr, cnt, csr, b1, Bf, BN);

    // layer 2: Ab = bf16(Bf@W2) ; out = gelu(agg(Ab) + b2)
    mfma_gemm_kernel<0><<<gB, 256, 0, stream>>>(Bf, Wt2, nullptr, Ab, nullptr, BN);
    agg_kernel<0><<<aggBlocks, 256, 0, stream>>>(Ab, dinvf, ptr, cnt, csr, b2, (float*)d_out, BN);
}

// Round 9
// 450.734 us; speedup vs baseline: 1.1127x; 1.1127x over previous
//
#include <hip/hip_runtime.h>
#include <math.h>

#define DIM 128
#define SCAN_CHUNK 4096  // 256 threads * 16 elems
#define NB_HALF 256      // GEMM blocks per matrix (grid-stride over row tiles)

typedef __attribute__((ext_vector_type(8))) short short8;
typedef __attribute__((ext_vector_type(4))) float f32x4;

__device__ __forceinline__ float gelu_exact(float v) {
    return 0.5f * v * (1.0f + erff(v * 0.70710678118654752f));
}

// round-to-nearest-even fp32 -> bf16 bits (finite inputs)
__device__ __forceinline__ unsigned short f2bf(float f) {
    unsigned int u = __float_as_uint(f);
    return (unsigned short)((u + 0x7FFFu + ((u >> 16) & 1u)) >> 16);
}
__device__ __forceinline__ float bf_lo(unsigned int v) { return __uint_as_float(v << 16); }
__device__ __forceinline__ float bf_hi(unsigned int v) { return __uint_as_float(v & 0xFFFF0000u); }

// ---------------- graph build ----------------
// packed[d]: high 32 = edge count, low 32 = sum(w) in 2^26 fixed point.
// One 64-bit atomic per edge; returned old high word = rank within segment.
// NOTE: standalone, 1 edge/thread, 4 VGPR — R7 showed mixing this with GEMM
// waves or chaining 2 edges/thread hurts.

__global__ void deg_cnt_kernel(const int* __restrict__ dst,
                               const float* __restrict__ w,
                               unsigned long long* __restrict__ packed,
                               int* __restrict__ rank, int E) {
    int e = blockIdx.x * blockDim.x + threadIdx.x;
    if (e >= E) return;
    int d = dst[e];
    unsigned long long inc =
        (1ull << 32) | (unsigned long long)(unsigned int)(w[e] * 67108864.0f);
    unsigned long long old = atomicAdd(&packed[d], inc);
    rank[e] = (int)(old >> 32);
}

// ---------------- weight transpose + bf16 (3 matrices, one launch) ----------------

__global__ __launch_bounds__(256) void wt3_kernel(const float* __restrict__ W1,
                                                  const float* __restrict__ Wres,
                                                  const float* __restrict__ W2,
                                                  unsigned short* __restrict__ Wt1,
                                                  unsigned short* __restrict__ Wtr,
                                                  unsigned short* __restrict__ Wt2) {
    int b = blockIdx.x;
    const float* W = (b < 64) ? W1 : (b < 128) ? Wres : W2;
    unsigned short* Wt = (b < 64) ? Wt1 : (b < 128) ? Wtr : Wt2;
    int idx = (b & 63) * 256 + threadIdx.x;  // idx = r*128 + c
    int r = idx >> 7, c = idx & 127;
    Wt[c * 128 + r] = f2bf(W[idx]);
}

// ---------------- MFMA GEMM, B-in-registers: [BN,128] @ [128,128] ----------------
// Each lane preloads its 32 B-fragments (128 VGPR = the whole 32 KB Wt across the
// wave) ONCE, then grid-strides over 64-row tiles: 8 A-loads + 32 reg-MFMA per tile.
// MODE 0: outb = bf16(X @ W)        MODE 2: Bf = 0.3f*(X@W + bias)   (init)

template <int MODE>
__device__ __forceinline__ void gemm_breg_body(const float* __restrict__ X,
                                               const unsigned short* __restrict__ Wt,
                                               const float* __restrict__ bias,
                                               unsigned short* __restrict__ outb,
                                               float* __restrict__ Bf,
                                               int BN, int t0, int tStride) {
    int tid = threadIdx.x;
    int wv = tid >> 6, l = tid & 63;
    int l15 = l & 15, kg = l >> 4;

    // B fragments: b[ks][nt] = 8 bf16 of col (nt*16+l15), k = ks*32+kg*8 ..+7
    uint4 b[4][8];
#pragma unroll
    for (int ks = 0; ks < 4; ks++)
#pragma unroll
        for (int nt = 0; nt < 8; nt++)
            b[ks][nt] = *(const uint4*)(Wt + (size_t)(nt * 16 + l15) * 128 + ks * 32 + kg * 8);

    float bias_r[8];
    if (MODE == 2) {
#pragma unroll
        for (int nt = 0; nt < 8; nt++) bias_r[nt] = bias[nt * 16 + l15];
    }

    int nTiles = (BN + 63) / 64;

    float4 aRaw[8];
    {   // prefetch first tile
        int rowA = t0 * 64 + wv * 16 + l15;
        if (rowA > BN - 1) rowA = BN - 1;
        const float* ap = X + (size_t)rowA * 128 + kg * 8;
#pragma unroll
        for (int ks = 0; ks < 4; ks++) {
            aRaw[2 * ks] = *(const float4*)(ap + ks * 32);
            aRaw[2 * ks + 1] = *(const float4*)(ap + ks * 32 + 4);
        }
    }

    for (int t = t0; t < nTiles; t += tStride) {
        // convert raw A -> bf16 frags (frees aRaw for the next prefetch)
        short8 aF[4];
#pragma unroll
        for (int ks = 0; ks < 4; ks++) {
            float4 a0 = aRaw[2 * ks], a1 = aRaw[2 * ks + 1];
            aF[ks][0] = (short)f2bf(a0.x); aF[ks][1] = (short)f2bf(a0.y);
            aF[ks][2] = (short)f2bf(a0.z); aF[ks][3] = (short)f2bf(a0.w);
            aF[ks][4] = (short)f2bf(a1.x); aF[ks][5] = (short)f2bf(a1.y);
            aF[ks][6] = (short)f2bf(a1.z); aF[ks][7] = (short)f2bf(a1.w);
        }
        // issue next tile's A loads; they complete under the MFMAs below
        int tn = t + tStride;
        if (tn < nTiles) {
            int rowA = tn * 64 + wv * 16 + l15;
            if (rowA > BN - 1) rowA = BN - 1;
            const float* ap = X + (size_t)rowA * 128 + kg * 8;
#pragma unroll
            for (int ks = 0; ks < 4; ks++) {
                aRaw[2 * ks] = *(const float4*)(ap + ks * 32);
                aRaw[2 * ks + 1] = *(const float4*)(ap + ks * 32 + 4);
            }
        }

        f32x4 acc[8];
#pragma unroll
        for (int nt = 0; nt < 8; nt++) acc[nt] = (f32x4){0.f, 0.f, 0.f, 0.f};
#pragma unroll
        for (int ks = 0; ks < 4; ks++)
#pragma unroll
            for (int nt = 0; nt < 8; nt++)
                acc[nt] = __builtin_amdgcn_mfma_f32_16x16x32_bf16(
                    aF[ks], __builtin_bit_cast(short8, b[ks][nt]), acc[nt], 0, 0, 0);

        int row0 = t * 64 + wv * 16;
#pragma unroll
        for (int nt = 0; nt < 8; nt++) {
            int col = nt * 16 + l15;
#pragma unroll
            for (int r = 0; r < 4; r++) {
                int row = row0 + kg * 4 + r;
                if (row >= BN) continue;
                size_t idx = (size_t)row * 128 + col;
                if (MODE == 0) outb[idx] = f2bf(acc[nt][r]);
                else           Bf[idx] = 0.3f * (acc[nt][r] + bias_r[nt]);
            }
        }
    }
}

// blocks [0,NB_HALF): x@W1 -> Ab ; [NB_HALF,2*NB_HALF): res-init -> Bf
__global__ __launch_bounds__(256, 2) void gemm2x_kernel(const float* __restrict__ x,
                                                        const unsigned short* __restrict__ Wt1,
                                                        const unsigned short* __restrict__ Wtr,
                                                        const float* __restrict__ bres,
                                                        unsigned short* __restrict__ Ab,
                                                        float* __restrict__ Bf, int BN) {
    int b = blockIdx.x;
    if (b < NB_HALF) gemm_breg_body<0>(x, Wt1, nullptr, Ab, nullptr, BN, b, NB_HALF);
    else             gemm_breg_body<2>(x, Wtr, bres, nullptr, Bf, BN, b - NB_HALF, NB_HALF);
}

__global__ __launch_bounds__(256, 2) void gemm1x_kernel(const float* __restrict__ X,
                                                        const unsigned short* __restrict__ Wt,
                                                        unsigned short* __restrict__ outb,
                                                        int BN) {
    gemm_breg_body<0>(X, Wt, nullptr, outb, nullptr, BN, blockIdx.x, 2 * NB_HALF);
}

// ---------------- scan stage A (fused with dinv/cnt unpack) ----------------

__global__ __launch_bounds__(256) void scanAD_kernel(const unsigned long long* __restrict__ packed,
                                                     float* __restrict__ dinvf,
                                                     int* __restrict__ cnt,
                                                     int* __restrict__ partials, int BN) {
    int tid = threadIdx.x;
    int base = blockIdx.x * SCAN_CHUNK;
    int sum = 0;
#pragma unroll
    for (int i = 0; i < 16; i++) {
        int ii = base + i * 256 + tid;
        if (ii < BN) {
            unsigned long long v = packed[ii];
            int c = (int)(v >> 32);
            cnt[ii] = c;
            dinvf[ii] = rsqrtf((float)(unsigned int)(v & 0xFFFFFFFFu) * (1.0f / 67108864.0f) + 1.0f);
            sum += c;
        }
    }
    __shared__ int lds[4];
#pragma unroll
    for (int off = 32; off; off >>= 1) sum += __shfl_down(sum, off, 64);
    if ((tid & 63) == 0) lds[tid >> 6] = sum;
    __syncthreads();
    if (tid == 0) partials[blockIdx.x] = lds[0] + lds[1] + lds[2] + lds[3];
}

__global__ __launch_bounds__(256) void scanB_kernel(int* __restrict__ partials, int nblk) {
    __shared__ int lds[256];
    int tid = threadIdx.x;
    int v = (tid < nblk) ? partials[tid] : 0;
    lds[tid] = v;
    __syncthreads();
#pragma unroll
    for (int off = 1; off < 256; off <<= 1) {
        int t = (tid >= off) ? lds[tid - off] : 0;
        __syncthreads();
        lds[tid] += t;
        __syncthreads();
    }
    if (tid < nblk) partials[tid] = lds[tid] - v;  // exclusive
}

__global__ __launch_bounds__(256) void scanC_kernel(const int* __restrict__ cnt,
                                                    const int* __restrict__ partials,
                                                    int* __restrict__ ptr, int BN) {
    __shared__ int lds[256];
    int tid = threadIdx.x;
    int base = blockIdx.x * SCAN_CHUNK;
    int idx0 = base + tid * 16;
    int v[16];
    int tsum = 0;
#pragma unroll
    for (int j = 0; j < 16; j++) {
        int ii = idx0 + j;
        v[j] = (ii < BN) ? cnt[ii] : 0;
        tsum += v[j];
    }
    lds[tid] = tsum;
    __syncthreads();
#pragma unroll
    for (int off = 1; off < 256; off <<= 1) {
        int t = (tid >= off) ? lds[tid - off] : 0;
        __syncthreads();
        lds[tid] += t;
        __syncthreads();
    }
    int excl = lds[tid] - tsum + partials[blockIdx.x];
#pragma unroll
    for (int j = 0; j < 16; j++) {
        int ii = idx0 + j;
        if (ii < BN) ptr[ii] = excl;
        excl += v[j];
    }
}

// atomic-free fill: pos = ptr[d] + rank[e]; one packed int2 {src, nrm} per edge
__global__ void fill_kernel(const int* __restrict__ ei, const float* __restrict__ w,
                            const int* __restrict__ rank, const int* __restrict__ ptr,
                            const float* __restrict__ dinvf,
                            int2* __restrict__ csr, int E) {
    int e = blockIdx.x * blockDim.x + threadIdx.x;
    if (e >= E) return;
    int s = ei[e];
    int d = ei[(size_t)E + e];
    int pos = ptr[d] + rank[e];
    float nrm = dinvf[s] * w[e] * dinvf[d];
    csr[pos] = make_int2(s, __float_as_int(nrm));
}

// ---------------- aggregation: half-wave (32 lanes) per node, bf16 gather, 4-deep ----
// ACCMODE 0: out = gelu(...)        ACCMODE 1: out += gelu(...)

template <int ACCMODE>
__global__ __launch_bounds__(256) void agg_kernel(const unsigned short* __restrict__ XWb,
                                                  const float* __restrict__ dinvf,
                                                  const int* __restrict__ ptr,
                                                  const int* __restrict__ cnt,
                                                  const int2* __restrict__ csr,
                                                  const float* __restrict__ bias,
                                                  float* __restrict__ out, int BN) {
    int h = threadIdx.x >> 5;        // half-wave id 0..7
    int lane = threadIdx.x & 31;     // lane within half-wave
    int n = blockIdx.x * 8 + h;
    if (n >= BN) return;
    int beg = ptr[n];
    int endv = beg + cnt[n];

    float4 a0 = make_float4(0.f, 0.f, 0.f, 0.f);
    float4 a1 = make_float4(0.f, 0.f, 0.f, 0.f);
    float4 a2 = make_float4(0.f, 0.f, 0.f, 0.f);
    float4 a3 = make_float4(0.f, 0.f, 0.f, 0.f);
    int i = beg;
    for (; i + 3 < endv; i += 4) {
        int2 e0 = csr[i], e1 = csr[i + 1], e2 = csr[i + 2], e3 = csr[i + 3];
        uint2 r0 = *(const uint2*)(XWb + (size_t)e0.x * 128 + lane * 4);
        uint2 r1 = *(const uint2*)(XWb + (size_t)e1.x * 128 + lane * 4);
        uint2 r2 = *(const uint2*)(XWb + (size_t)e2.x * 128 + lane * 4);
        uint2 r3 = *(const uint2*)(XWb + (size_t)e3.x * 128 + lane * 4);
        float n0 = __int_as_float(e0.y), n1 = __int_as_float(e1.y);
        float n2 = __int_as_float(e2.y), n3 = __int_as_float(e3.y);
        a0.x += n0 * bf_lo(r0.x); a0.y += n0 * bf_hi(r0.x);
        a0.z += n0 * bf_lo(r0.y); a0.w += n0 * bf_hi(r0.y);
        a1.x += n1 * bf_lo(r1.x); a1.y += n1 * bf_hi(r1.x);
        a1.z += n1 * bf_lo(r1.y); a1.w += n1 * bf_hi(r1.y);
        a2.x += n2 * bf_lo(r2.x); a2.y += n2 * bf_hi(r2.x);
        a2.z += n2 * bf_lo(r2.y); a2.w += n2 * bf_hi(r2.y);
        a3.x += n3 * bf_lo(r3.x); a3.y += n3 * bf_hi(r3.x);
        a3.z += n3 * bf_lo(r3.y); a3.w += n3 * bf_hi(r3.y);
    }
    for (; i < endv; i++) {
        int2 e0 = csr[i];
        uint2 r0 = *(const uint2*)(XWb + (size_t)e0.x * 128 + lane * 4);
        float n0 = __int_as_float(e0.y);
        a0.x += n0 * bf_lo(r0.x); a0.y += n0 * bf_hi(r0.x);
        a0.z += n0 * bf_lo(r0.y); a0.w += n0 * bf_hi(r0.y);
    }
    float dn = dinvf[n];
    float sl = dn * dn;
    uint2 rs = *(const uint2*)(XWb + (size_t)n * 128 + lane * 4);
    float4 bb = ((const float4*)bias)[lane];
    float4 o;
    o.x = gelu_exact(a0.x + a1.x + a2.x + a3.x + sl * bf_lo(rs.x) + bb.x);
    o.y = gelu_exact(a0.y + a1.y + a2.y + a3.y + sl * bf_hi(rs.x) + bb.y);
    o.z = gelu_exact(a0.z + a1.z + a2.z + a3.z + sl * bf_lo(rs.y) + bb.z);
    o.w = gelu_exact(a0.w + a1.w + a2.w + a3.w + sl * bf_hi(rs.y) + bb.w);
    float4* op = (float4*)(out + (size_t)n * 128) + lane;
    if (ACCMODE == 1) {
        float4 prev = *op;
        o.x += prev.x; o.y += prev.y; o.z += prev.z; o.w += prev.w;
    }
    *op = o;
}

// ---------------- launch ----------------

extern "C" void kernel_launch(void* const* d_in, const int* in_sizes, int n_in,
                              void* d_out, int out_size, void* d_ws, size_t ws_size,
                              hipStream_t stream) {
    const float* x = (const float*)d_in[0];
    const int* ei = (const int*)d_in[1];        // harness passes integers as int32
    const float* w = (const float*)d_in[5];
    const float* W1 = (const float*)d_in[7];
    const float* b1 = (const float*)d_in[8];
    const float* W2 = (const float*)d_in[9];
    const float* b2 = (const float*)d_in[10];
    const float* Wres = (const float*)d_in[11];
    const float* bres = (const float*)d_in[12];

    const int BN = in_sizes[0] / DIM;
    const int E = in_sizes[1] / 2;
    const int NBLK = (BN + SCAN_CHUNK - 1) / SCAN_CHUNK;

    // workspace layout (16B aligned); h-buffer lives in d_out.
    char* p = (char*)d_ws;
    unsigned short* Ab = (unsigned short*)p;         p += (size_t)BN * DIM * 2;  // bf16 XW
    unsigned long long* packed = (unsigned long long*)p;  p += (size_t)BN * 8;
    float* dinvf = (float*)p;          p += (size_t)BN * 4;
    int* cnt = (int*)p;                p += (size_t)BN * 4;
    int* ptr = (int*)p;                p += (size_t)BN * 4;
    int* partials = (int*)p;           p += 1024;
    unsigned short* Wt1 = (unsigned short*)p;   p += 128 * 128 * 2;
    unsigned short* Wtr = (unsigned short*)p;   p += 128 * 128 * 2;
    unsigned short* Wt2 = (unsigned short*)p;   p += 128 * 128 * 2;
    int* rank = (int*)p;               p += (size_t)E * 4;
    int2* csr = (int2*)p;              p += (size_t)E * 8;

    float* Bf = (float*)d_out;         // h buffer; fully written by res-init

    const int* dst32 = ei + E;

    hipMemsetAsync(packed, 0, (size_t)BN * 8, stream);

    int tE = (E + 255) / 256;
    int aggBlocks = (BN + 7) / 8;

    deg_cnt_kernel<<<tE, 256, 0, stream>>>(dst32, w, packed, rank, E);
    wt3_kernel<<<192, 256, 0, stream>>>(W1, Wres, W2, Wt1, Wtr, Wt2);

    // Ab = bf16(x@W1)  and  Bf = 0.3*(x@Wres+bres)  (B-in-reg, grid-stride)
    gemm2x_kernel<<<2 * NB_HALF, 256, 0, stream>>>(x, Wt1, Wtr, bres, Ab, Bf, BN);

    scanAD_kernel<<<NBLK, 256, 0, stream>>>(packed, dinvf, cnt, partials, BN);
    scanB_kernel<<<1, 256, 0, stream>>>(partials, NBLK);
    scanC_kernel<<<NBLK, 256, 0, stream>>>(cnt, partials, ptr, BN);
    fill_kernel<<<tE, 256, 0, stream>>>(ei, w, rank, ptr, dinvf, csr, E);

    // layer 1 finish: Bf += gelu(agg(Ab) + b1)
    agg_kernel<1><<<aggBlocks, 256, 0, stream>>>(Ab, dinvf, ptr, cnt, csr, b1, Bf, BN);

    // layer 2: Ab = bf16(Bf@W2) ; out = gelu(agg(Ab) + b2)
    gemm1x_kernel<<<2 * NB_HALF, 256, 0, stream>>>(Bf, Wt2, Ab, BN);
    agg_kernel<0><<<aggBlocks, 256, 0, stream>>>(Ab, dinvf, ptr, cnt, csr, b2, (float*)d_out, BN);
}